// Round 4
// baseline (1781.781 us; speedup 1.0000x reference)
//
#include <hip/hip_runtime.h>
#include <stdint.h>

#define NPTS   32768
#define NBATCH 8
#define NFPS   512
#define NGRP   32
#define BIGF   1e10f
#define R2F    0.04f
#define CAP    512
#define QPB    8      // ball-query centroids per block

// ---------------------------------------------------------------------------
// FPS: ONE block per batch (P=1), no mailbox / device-scope traffic.
// R1-R3: VGPR budget stuck at 64 (launch_bounds(,4) and waves_per_eu(4,4)
// both silently ignored; binary identical) -> 96 persistent regs partially
// spill. BUT VALUBusy=2.38% on 3.125% active CUs => ~76% VALU-busy: the
// loop is VALU-issue-bound, so this round CUTS the VALU stream ~2x:
//  * v_pk_add/mul_f32 packed fp32 (2 lanes/op, bit-exact IEEE per lane;
//    x+(-c) == x-c exactly; mul/add kept separate = reference order)
//  * no index tracking in hot loop, no u64 reduces: float-only max chain;
//    winner thread(s) (vmaxT==blockmax) rescan their 32 dists for ==M and
//    atomicMin the global index -> exact first-occurrence tie-break
//    (min gi among dist==M), one extra cheap barrier.
// Occupancy knob attempt #3: raw amdgpu_flat_work_group_size(1024,1024) +
// amdgpu_waves_per_eu(4) (no __launch_bounds__). If it lands: 128-VGPR
// budget, no spills. If not, the VALU cut still pays.
// 32 pts/thread: x,y,dist in VGPRs (96, asm-pinned vs remat -- R5/R6
// lesson), z in 128KB static LDS (read-only, contiguous ds_read_b128).
// Winner coords: readfirstlane(far) -> uniform load, L2-hot.
// ---------------------------------------------------------------------------
#define THR    1024               // threads per fps block
#define NCH    8                  // float4-chunks per thread -> 32 pts/thread

typedef unsigned long long u64;
typedef float v2f __attribute__((ext_vector_type(2)));

__device__ __forceinline__ v2f pk_add(v2f a, v2f b) {
    v2f d;
    asm("v_pk_add_f32 %0, %1, %2" : "=v"(d) : "v"(a), "v"(b));
    return d;
}
__device__ __forceinline__ v2f pk_mul(v2f a, v2f b) {
    v2f d;
    asm("v_pk_mul_f32 %0, %1, %2" : "=v"(d) : "v"(a), "v"(b));
    return d;
}

__attribute__((amdgpu_flat_work_group_size(THR, THR), amdgpu_waves_per_eu(4)))
__global__ void fps_kernel(
    const float* __restrict__ xyz,
    const int* __restrict__ finit,
    int* __restrict__ cidx)        // [NBATCH][NFPS]
{
#pragma clang fp contract(off)
    const int b = blockIdx.x;
    const int t = threadIdx.x;
    const float* __restrict__ base = xyz + (size_t)b * (NPTS * 3);

    __shared__ float4 zs4[NPTS / 4];   // 128 KB: z coords, written once
    __shared__ float redM[2][16];      // per-wave maxima, parity dbuf
    __shared__ int   winBox[2];        // argmax slot, parity dbuf

    v2f xr2[2 * NCH], yr2[2 * NCH], dist2[2 * NCH];   // 96 VGPRs persistent
    {
        const float4* __restrict__ g4 = reinterpret_cast<const float4*>(base);
#pragma unroll
        for (int j = 0; j < NCH; ++j) {
            const int c = j * THR + t;              // chunk: coalesced (48B/lane)
            const float4 q0 = g4[3 * c + 0];
            const float4 q1 = g4[3 * c + 1];
            const float4 q2 = g4[3 * c + 2];
            v2f a;
            a.x = q0.x; a.y = q0.w;  xr2[2 * j]     = a;   // x of pts 4c+0,1
            a.x = q1.z; a.y = q2.y;  xr2[2 * j + 1] = a;   // x of pts 4c+2,3
            a.x = q0.y; a.y = q1.x;  yr2[2 * j]     = a;
            a.x = q1.w; a.y = q2.z;  yr2[2 * j + 1] = a;
            zs4[c] = make_float4(q0.z, q1.y, q2.x, q2.w);
            a.x = BIGF; a.y = BIGF;
            dist2[2 * j] = a; dist2[2 * j + 1] = a;
        }
    }
    // pin coords into live VGPRs: an asm result cannot be rematerialized
    // (R5/R6: allocator otherwise re-issues the global loads per iteration)
#pragma unroll
    for (int i = 0; i < 2 * NCH; ++i) {
        asm("" : "+v"(xr2[i]), "+v"(yr2[i]));
    }

    int far = finit[b];
    float cx = base[3 * far + 0];
    float cy = base[3 * far + 1];
    float cz = base[3 * far + 2];

    const int wid  = t >> 6;
    const int lane = t & 63;
    if (t == 0) { winBox[0] = 0x7fffffff; winBox[1] = 0x7fffffff; }
    __syncthreads();                    // zs4 + winBox published

    for (int it = 0; it < NFPS; ++it) {
        if (t == 0) cidx[b * NFPS + it] = far;   // record BEFORE update
        if (it == NFPS - 1) break;               // last far never used
        const int p = it & 1;

        v2f ncx2; ncx2.x = -cx; ncx2.y = -cx;
        v2f ncy2; ncy2.x = -cy; ncy2.y = -cy;
        v2f ncz2; ncz2.x = -cz; ncz2.y = -cz;
        float vm0 = -1.0f, vm1 = -1.0f;
#pragma unroll
        for (int j = 0; j < NCH; ++j) {
            const float4 zq = zs4[j * THR + t];  // ds_read_b128, conflict-free
            {   // pair 0: local points 4j+0, 4j+1
                v2f z2; z2.x = zq.x; z2.y = zq.y;
                v2f dx = pk_add(xr2[2 * j], ncx2);
                v2f dy = pk_add(yr2[2 * j], ncy2);
                v2f dz = pk_add(z2, ncz2);
                v2f s0 = pk_mul(dx, dx);
                v2f s1 = pk_mul(dy, dy);
                v2f d  = pk_add(s0, s1);
                v2f s2 = pk_mul(dz, dz);
                d = pk_add(d, s2);
                float d0 = fminf(dist2[2 * j].x, d.x);
                float d1 = fminf(dist2[2 * j].y, d.y);
                dist2[2 * j].x = d0; dist2[2 * j].y = d1;
                vm0 = fmaxf(vm0, d0); vm1 = fmaxf(vm1, d1);
            }
            {   // pair 1: local points 4j+2, 4j+3
                v2f z2; z2.x = zq.z; z2.y = zq.w;
                v2f dx = pk_add(xr2[2 * j + 1], ncx2);
                v2f dy = pk_add(yr2[2 * j + 1], ncy2);
                v2f dz = pk_add(z2, ncz2);
                v2f s0 = pk_mul(dx, dx);
                v2f s1 = pk_mul(dy, dy);
                v2f d  = pk_add(s0, s1);
                v2f s2 = pk_mul(dz, dz);
                d = pk_add(d, s2);
                float d0 = fminf(dist2[2 * j + 1].x, d.x);
                float d1 = fminf(dist2[2 * j + 1].y, d.y);
                dist2[2 * j + 1].x = d0; dist2[2 * j + 1].y = d1;
                vm0 = fmaxf(vm0, d0); vm1 = fmaxf(vm1, d1);
            }
        }
        const float vmaxT = fmaxf(vm0, vm1);

        // wave max (float only -- 6 shuffles, half the old u64 chain)
        float wm = vmaxT;
#pragma unroll
        for (int off = 32; off >= 1; off >>= 1)
            wm = fmaxf(wm, __shfl_xor(wm, off, 64));
        if (lane == 0) redM[p][wid] = wm;
        __syncthreads();                 // barrier 1: redM[p], winBox[p] ready

        // block max, redundantly in every wave (deterministic same-bits tree)
        float bm = redM[p][lane & 15];
#pragma unroll
        for (int off = 8; off >= 1; off >>= 1)
            bm = fmaxf(bm, __shfl_xor(bm, off, 64));

        // only winner thread(s) recover the index: min gi with dist==bm
        if (vmaxT == bm) {
            int best = 0x7fffffff;
#pragma unroll
            for (int i = 0; i < 2 * NCH; ++i) {
                const int gi0 = ((i >> 1) << 12) + (t << 2) + ((i & 1) << 1);
                if (dist2[i].x == bm) best = min(best, gi0);
                if (dist2[i].y == bm) best = min(best, gi0 + 1);
            }
            atomicMin(&winBox[p], best);
        }
        __syncthreads();                 // barrier 2: winBox[p] final

        far = winBox[p];
        if (t == 0) winBox[p ^ 1] = 0x7fffffff;   // re-init other parity
        far = __builtin_amdgcn_readfirstlane(far);
        cx = base[3 * far + 0];          // uniform, L2-hot
        cy = base[3 * far + 1];
        cz = base[3 * far + 2];
    }
}

// ---------------------------------------------------------------------------
// Ball query + grouping: QPB=8 centroids per block (unchanged, proven).
// ---------------------------------------------------------------------------
__global__ __launch_bounds__(256) void ballq_kernel(
    const float* __restrict__ xyz,
    const int* __restrict__ cidx,
    float* __restrict__ out0,      // [B][S][33][3]
    float* __restrict__ out1)      // [B][S][3]
{
#pragma clang fp contract(off)
    const int blk0 = blockIdx.x * QPB;   // first global centroid (b*NFPS+s)
    const int b    = blk0 >> 9;          // QPB divides 512 -> same batch
    const int t    = threadIdx.x;
    const float* __restrict__ base = xyz + (size_t)b * (NPTS * 3);

    __shared__ u64 list[QPB][CAP];       // 32 KB
    __shared__ int scnt[QPB];
    __shared__ u64 mask0[QPB];
    __shared__ int selIdx[QPB][NGRP];

    if (t < QPB) scnt[t] = 0;

    float cxs[QPB], cys[QPB], czs[QPB];
#pragma unroll
    for (int q = 0; q < QPB; ++q) {
        const int ci = cidx[blk0 + q];
        cxs[q] = base[3 * ci + 0];
        cys[q] = base[3 * ci + 1];
        czs[q] = base[3 * ci + 2];
    }
    __syncthreads();

    // in-ball masks for the first 64 indices (fill candidates); wave 0 only
    if (t < 64) {
        const float px = base[3 * t + 0];
        const float py = base[3 * t + 1];
        const float pz = base[3 * t + 2];
#pragma unroll
        for (int q = 0; q < QPB; ++q) {
            float dx = px - cxs[q];
            float dy = py - cys[q];
            float dz = pz - czs[q];
            float d  = dx * dx + dy * dy;
            d = d + dz * dz;
            u64 mk = __ballot(d <= R2F);
            if (t == 0) mask0[q] = mk;
        }
    }

    // scan all points once; test against all QPB centroids
    for (int k = 0; k < NPTS / 256; ++k) {
        const int p = k * 256 + t;
        const float px = base[3 * p + 0];
        const float py = base[3 * p + 1];
        const float pz = base[3 * p + 2];
#pragma unroll
        for (int q = 0; q < QPB; ++q) {
            float dx = px - cxs[q];
            float dy = py - cys[q];
            float dz = pz - czs[q];
            float d  = dx * dx + dy * dy;
            d = d + dz * dz;
            if (d <= R2F) {
                int pos = atomicAdd(&scnt[q], 1);
                if (pos < CAP)
                    list[q][pos] = (((u64)__float_as_uint(d)) << 32)
                                   | (unsigned)p;
            }
        }
    }
    __syncthreads();

    // rank-based selection, 2 centroids per wave:
    // key's rank == #smaller keys (keys unique via idx)
    {
        const int lane = t & 63;
        for (int q = t >> 6; q < QPB; q += 4) {
            const int m = min(scnt[q], CAP);
            for (int j = lane; j < m; j += 64) {
                const u64 kj = list[q][j];
                int rank = 0;
                for (int i = 0; i < m; ++i) rank += (list[q][i] < kj) ? 1 : 0;
                if (rank < NGRP) selIdx[q][rank] = (int)(kj & 0xffffffffu);
            }
        }
    }
    __syncthreads();

    for (int s = t; s < 33 * QPB; s += 256) {
        const int q    = s / 33;
        const int slot = s % 33;
        const int sg   = blk0 + q;
        const float cx = cxs[q], cy = cys[q], cz = czs[q];
        const size_t o0 = (size_t)sg * 33 * 3;
        if (slot == 32) {
            out0[o0 + 0] = cx; out0[o0 + 1] = cy; out0[o0 + 2] = cz;
            const size_t o1 = (size_t)sg * 3;
            out1[o1 + 0] = cx; out1[o1 + 1] = cy; out1[o1 + 2] = cz;
        } else {
            const int m = min(scnt[q], CAP);
            const int K = min(m, NGRP);
            int idx;
            if (slot < K) {
                idx = selIdx[q][slot];
            } else {
                // (slot-K+1)-th zero bit of mask0 = next out-of-radius index
                u64 zeros = ~mask0[q];
                const int need = slot - K;
                for (int z = 0; z < need; ++z) zeros &= zeros - 1;
                idx = __builtin_ctzll(zeros);
            }
            const float px = base[3 * idx + 0];
            const float py = base[3 * idx + 1];
            const float pz = base[3 * idx + 2];
            out0[o0 + (size_t)(1 + slot) * 3 + 0] = px - cx;
            out0[o0 + (size_t)(1 + slot) * 3 + 1] = py - cy;
            out0[o0 + (size_t)(1 + slot) * 3 + 2] = pz - cz;
        }
    }
}

extern "C" void kernel_launch(void* const* d_in, const int* in_sizes, int n_in,
                              void* d_out, int out_size, void* d_ws, size_t ws_size,
                              hipStream_t stream) {
    const float* xyz   = (const float*)d_in[0];
    const int*   finit = (const int*)d_in[1];
    float* out0 = (float*)d_out;
    float* out1 = out0 + (size_t)NBATCH * NFPS * 33 * 3;

    // ws layout: cidx 16 KB (mailbox no longer needed -- P=1 FPS)
    int* cidx = (int*)d_ws;

    fps_kernel<<<NBATCH, THR, 0, stream>>>(xyz, finit, cidx);
    ballq_kernel<<<(NBATCH * NFPS) / QPB, 256, 0, stream>>>(xyz, cidx, out0, out1);
}

// Round 5
// 1514.598 us; speedup vs baseline: 1.1764x; 1.1764x over previous
//
#include <hip/hip_runtime.h>
#include <stdint.h>

#define NPTS   32768
#define NBATCH 8
#define NFPS   512
#define NGRP   32
#define BIGF   1e10f
#define R2F    0.04f
#define CAP    512
#define QPB    8      // ball-query centroids per block

// ---------------------------------------------------------------------------
// FPS: ONE block per batch (P=1), no mailbox / device-scope traffic.
// R1-R4 post-mortem: VGPR_Count stuck at 64 across every occupancy
// attribute => the v2f ARRAYS were never SROA-promoted (asm pin on
// runtime-indexed element keeps the alloca addressed) -> all "persistent"
// state lived in scratch; attributes were irrelevant; R4's pk-asm added
// copies on top of scratch traffic (regression). The backend budget
// already allows 128 VGPRs here (128KB LDS -> 1 WG/CU -> 4 waves/EU).
// Fix: NO ARRAYS. 48 named v2f SSA values (X0..15, Y0..15, D0..15),
// macro-expanded init/step/rescan -- nothing for SROA to miss; the
// allocator must carry them in VGPRs (demand ~116 <= 128 budget).
// Plain v2f arithmetic (R4's pk-asm reverted). Float-only block max +
// winner-rescan argmax: exact first-occurrence tie-break via atomicMin
// of min-gi among dist==max (jnp.argmax = first max).
// Distance math bit-exact vs reference: contract off, (dx^2+dy^2)+dz^2,
// fminf accumulate. z coords in 128KB static LDS (written once,
// ds_read_b128 conflict-free). Winner coords: uniform L2-hot load.
// ---------------------------------------------------------------------------
#define THR    1024               // threads per fps block

typedef unsigned long long u64;
typedef float v2f __attribute__((ext_vector_type(2)));

__device__ __forceinline__ u64 shfl_xor_u64(u64 v, int off) {
    unsigned lo = (unsigned)v, hi = (unsigned)(v >> 32);
    lo = __shfl_xor(lo, off, 64);
    hi = __shfl_xor(hi, off, 64);
    return ((u64)hi << 32) | lo;
}

__attribute__((amdgpu_flat_work_group_size(THR, THR), amdgpu_waves_per_eu(4, 4)))
__global__ void fps_kernel(
    const float* __restrict__ xyz,
    const int* __restrict__ finit,
    int* __restrict__ cidx)        // [NBATCH][NFPS]
{
#pragma clang fp contract(off)
    const int b = blockIdx.x;
    const int t = threadIdx.x;
    const float* __restrict__ base = xyz + (size_t)b * (NPTS * 3);

    __shared__ float4 zs4[NPTS / 4];   // 128 KB: z coords, written once
    __shared__ float redM[2][16];      // per-wave maxima, parity dbuf
    __shared__ int   winBox[2];        // argmax box, parity dbuf

    // 48 named persistent v2f values: X/Y coords + running min-dist.
    v2f X0,X1,X2,X3,X4,X5,X6,X7,X8,X9,X10,X11,X12,X13,X14,X15;
    v2f Y0,Y1,Y2,Y3,Y4,Y5,Y6,Y7,Y8,Y9,Y10,Y11,Y12,Y13,Y14,Y15;
    v2f D0,D1,D2,D3,D4,D5,D6,D7,D8,D9,D10,D11,D12,D13,D14,D15;

    {
        const float4* __restrict__ g4 = reinterpret_cast<const float4*>(base);
#define LOADJ(j, A, B) { \
        const int c = (j) * THR + t;             /* coalesced 48B/lane */ \
        const float4 q0 = g4[3 * c + 0]; \
        const float4 q1 = g4[3 * c + 1]; \
        const float4 q2 = g4[3 * c + 2]; \
        X##A.x = q0.x; X##A.y = q0.w;  X##B.x = q1.z; X##B.y = q2.y; \
        Y##A.x = q0.y; Y##A.y = q1.x;  Y##B.x = q1.w; Y##B.y = q2.z; \
        zs4[c] = make_float4(q0.z, q1.y, q2.x, q2.w); \
        D##A.x = BIGF; D##A.y = BIGF;  D##B.x = BIGF; D##B.y = BIGF; \
    }
        LOADJ(0, 0, 1)  LOADJ(1, 2, 3)  LOADJ(2, 4, 5)  LOADJ(3, 6, 7)
        LOADJ(4, 8, 9)  LOADJ(5, 10, 11) LOADJ(6, 12, 13) LOADJ(7, 14, 15)
#undef LOADJ
    }
    // pin against load-rematerialization (R5/R6 lesson); named SSA values,
    // so these pins act on the real registers, not scratch reload temps.
    asm("" : "+v"(X0), "+v"(X1), "+v"(X2), "+v"(X3));
    asm("" : "+v"(X4), "+v"(X5), "+v"(X6), "+v"(X7));
    asm("" : "+v"(X8), "+v"(X9), "+v"(X10), "+v"(X11));
    asm("" : "+v"(X12), "+v"(X13), "+v"(X14), "+v"(X15));
    asm("" : "+v"(Y0), "+v"(Y1), "+v"(Y2), "+v"(Y3));
    asm("" : "+v"(Y4), "+v"(Y5), "+v"(Y6), "+v"(Y7));
    asm("" : "+v"(Y8), "+v"(Y9), "+v"(Y10), "+v"(Y11));
    asm("" : "+v"(Y12), "+v"(Y13), "+v"(Y14), "+v"(Y15));

    int far = finit[b];
    float cx = base[3 * far + 0];
    float cy = base[3 * far + 1];
    float cz = base[3 * far + 2];

    const int wid  = t >> 6;
    const int lane = t & 63;
    if (t == 0) { winBox[0] = 0x7fffffff; winBox[1] = 0x7fffffff; }
    __syncthreads();                    // zs4 + winBox published

    for (int it = 0; it < NFPS; ++it) {
        if (t == 0) cidx[b * NFPS + it] = far;   // record BEFORE update
        if (it == NFPS - 1) break;               // last far never used
        const int p = it & 1;

        v2f cx2; cx2.x = cx; cx2.y = cx;
        v2f cy2; cy2.x = cy; cy2.y = cy;
        v2f cz2; cz2.x = cz; cz2.y = cz;
        float vm0 = -1.0f, vm1 = -1.0f;

#define HALF(A, z0, z1) { \
        v2f z2; z2.x = (z0); z2.y = (z1); \
        v2f dx = X##A - cx2; \
        v2f dy = Y##A - cy2; \
        v2f dz = z2 - cz2; \
        v2f s0 = dx * dx; \
        v2f s1 = dy * dy; \
        v2f d  = s0 + s1; \
        v2f s2 = dz * dz; \
        d = d + s2; \
        float d0 = fminf(D##A.x, d.x); \
        float d1 = fminf(D##A.y, d.y); \
        D##A.x = d0; D##A.y = d1; \
        vm0 = fmaxf(vm0, d0); vm1 = fmaxf(vm1, d1); \
    }
#define STEP(j, A, B) { \
        const float4 zq = zs4[(j) * THR + t];    /* ds_read_b128 */ \
        HALF(A, zq.x, zq.y) \
        HALF(B, zq.z, zq.w) \
    }
        STEP(0, 0, 1)  STEP(1, 2, 3)  STEP(2, 4, 5)  STEP(3, 6, 7)
        STEP(4, 8, 9)  STEP(5, 10, 11) STEP(6, 12, 13) STEP(7, 14, 15)
#undef STEP
#undef HALF
        const float vmaxT = fmaxf(vm0, vm1);

        // wave max (float-only, 6 shuffles)
        float wm = vmaxT;
#pragma unroll
        for (int off = 32; off >= 1; off >>= 1)
            wm = fmaxf(wm, __shfl_xor(wm, off, 64));
        if (lane == 0) redM[p][wid] = wm;
        __syncthreads();                 // barrier 1: redM[p] ready

        // block max, redundantly in every wave (exact: max is order-free)
        float bm = redM[p][lane & 15];
#pragma unroll
        for (int off = 8; off >= 1; off >>= 1)
            bm = fmaxf(bm, __shfl_xor(bm, off, 64));

        // only winner thread(s) recover the index: min gi with dist==bm
        if (vmaxT == bm) {
            int best = 0x7fffffff;
#define RES(i, A) { \
            const int gi0 = (((i) >> 1) << 12) + (t << 2) + (((i) & 1) << 1); \
            if (D##A.x == bm) best = min(best, gi0); \
            if (D##A.y == bm) best = min(best, gi0 + 1); \
        }
            RES(0, 0)  RES(1, 1)  RES(2, 2)  RES(3, 3)
            RES(4, 4)  RES(5, 5)  RES(6, 6)  RES(7, 7)
            RES(8, 8)  RES(9, 9)  RES(10, 10) RES(11, 11)
            RES(12, 12) RES(13, 13) RES(14, 14) RES(15, 15)
#undef RES
            atomicMin(&winBox[p], best);
        }
        __syncthreads();                 // barrier 2: winBox[p] final

        far = winBox[p];
        if (t == 0) winBox[p ^ 1] = 0x7fffffff;   // re-arm other parity
        far = __builtin_amdgcn_readfirstlane(far);
        cx = base[3 * far + 0];          // uniform, L2-hot
        cy = base[3 * far + 1];
        cz = base[3 * far + 2];
    }
}

// ---------------------------------------------------------------------------
// Ball query + grouping: QPB=8 centroids per block (unchanged, proven).
// ---------------------------------------------------------------------------
__global__ __launch_bounds__(256) void ballq_kernel(
    const float* __restrict__ xyz,
    const int* __restrict__ cidx,
    float* __restrict__ out0,      // [B][S][33][3]
    float* __restrict__ out1)      // [B][S][3]
{
#pragma clang fp contract(off)
    const int blk0 = blockIdx.x * QPB;   // first global centroid (b*NFPS+s)
    const int b    = blk0 >> 9;          // QPB divides 512 -> same batch
    const int t    = threadIdx.x;
    const float* __restrict__ base = xyz + (size_t)b * (NPTS * 3);

    __shared__ u64 list[QPB][CAP];       // 32 KB
    __shared__ int scnt[QPB];
    __shared__ u64 mask0[QPB];
    __shared__ int selIdx[QPB][NGRP];

    if (t < QPB) scnt[t] = 0;

    float cxs[QPB], cys[QPB], czs[QPB];
#pragma unroll
    for (int q = 0; q < QPB; ++q) {
        const int ci = cidx[blk0 + q];
        cxs[q] = base[3 * ci + 0];
        cys[q] = base[3 * ci + 1];
        czs[q] = base[3 * ci + 2];
    }
    __syncthreads();

    // in-ball masks for the first 64 indices (fill candidates); wave 0 only
    if (t < 64) {
        const float px = base[3 * t + 0];
        const float py = base[3 * t + 1];
        const float pz = base[3 * t + 2];
#pragma unroll
        for (int q = 0; q < QPB; ++q) {
            float dx = px - cxs[q];
            float dy = py - cys[q];
            float dz = pz - czs[q];
            float d  = dx * dx + dy * dy;
            d = d + dz * dz;
            u64 mk = __ballot(d <= R2F);
            if (t == 0) mask0[q] = mk;
        }
    }

    // scan all points once; test against all QPB centroids
    for (int k = 0; k < NPTS / 256; ++k) {
        const int p = k * 256 + t;
        const float px = base[3 * p + 0];
        const float py = base[3 * p + 1];
        const float pz = base[3 * p + 2];
#pragma unroll
        for (int q = 0; q < QPB; ++q) {
            float dx = px - cxs[q];
            float dy = py - cys[q];
            float dz = pz - czs[q];
            float d  = dx * dx + dy * dy;
            d = d + dz * dz;
            if (d <= R2F) {
                int pos = atomicAdd(&scnt[q], 1);
                if (pos < CAP)
                    list[q][pos] = (((u64)__float_as_uint(d)) << 32)
                                   | (unsigned)p;
            }
        }
    }
    __syncthreads();

    // rank-based selection, 2 centroids per wave:
    // key's rank == #smaller keys (keys unique via idx)
    {
        const int lane = t & 63;
        for (int q = t >> 6; q < QPB; q += 4) {
            const int m = min(scnt[q], CAP);
            for (int j = lane; j < m; j += 64) {
                const u64 kj = list[q][j];
                int rank = 0;
                for (int i = 0; i < m; ++i) rank += (list[q][i] < kj) ? 1 : 0;
                if (rank < NGRP) selIdx[q][rank] = (int)(kj & 0xffffffffu);
            }
        }
    }
    __syncthreads();

    for (int s = t; s < 33 * QPB; s += 256) {
        const int q    = s / 33;
        const int slot = s % 33;
        const int sg   = blk0 + q;
        const float cx = cxs[q], cy = cys[q], cz = czs[q];
        const size_t o0 = (size_t)sg * 33 * 3;
        if (slot == 32) {
            out0[o0 + 0] = cx; out0[o0 + 1] = cy; out0[o0 + 2] = cz;
            const size_t o1 = (size_t)sg * 3;
            out1[o1 + 0] = cx; out1[o1 + 1] = cy; out1[o1 + 2] = cz;
        } else {
            const int m = min(scnt[q], CAP);
            const int K = min(m, NGRP);
            int idx;
            if (slot < K) {
                idx = selIdx[q][slot];
            } else {
                // (slot-K+1)-th zero bit of mask0 = next out-of-radius index
                u64 zeros = ~mask0[q];
                const int need = slot - K;
                for (int z = 0; z < need; ++z) zeros &= zeros - 1;
                idx = __builtin_ctzll(zeros);
            }
            const float px = base[3 * idx + 0];
            const float py = base[3 * idx + 1];
            const float pz = base[3 * idx + 2];
            out0[o0 + (size_t)(1 + slot) * 3 + 0] = px - cx;
            out0[o0 + (size_t)(1 + slot) * 3 + 1] = py - cy;
            out0[o0 + (size_t)(1 + slot) * 3 + 2] = pz - cz;
        }
    }
}

extern "C" void kernel_launch(void* const* d_in, const int* in_sizes, int n_in,
                              void* d_out, int out_size, void* d_ws, size_t ws_size,
                              hipStream_t stream) {
    const float* xyz   = (const float*)d_in[0];
    const int*   finit = (const int*)d_in[1];
    float* out0 = (float*)d_out;
    float* out1 = out0 + (size_t)NBATCH * NFPS * 33 * 3;

    // ws layout: cidx 16 KB (no mailbox -- P=1 FPS)
    int* cidx = (int*)d_ws;

    fps_kernel<<<NBATCH, THR, 0, stream>>>(xyz, finit, cidx);
    ballq_kernel<<<(NBATCH * NFPS) / QPB, 256, 0, stream>>>(xyz, cidx, out0, out1);
}